// Round 9
// baseline (420.442 us; speedup 1.0000x reference)
//
#include <hip/hip_runtime.h>

// ---------------------------------------------------------------------------
// GNNWithPrompt, f32 I/O. Hi-only bf16 activations, hi+lo bf16 weights.
// k_prep: blocks 0..63 misc (detect+weight splits+out-init); blocks 64+
// XCD-partitioned count+rank (partition p only touches its dst range ->
// counter lines stay in one L2; no cross-XCD atomic ping-pong).
// k_gemm_p: frozen R6 persistent pipelined form. k_g: MT=64 L0 / 32 cls.
// Scatter: rank-based (atomic-free) + 8-way XCD dst-partitioning.
// ---------------------------------------------------------------------------

#define N0v 200000
#define N1v 50000
#define N2v 10000
#define E0v 800000
#define E1v 160000
#define TB0 49            // graph0 scan tiles (1024 each)
#define TB1 10            // graph1 scan tiles
#define TBL (TB0 + TB1)
#define NTILE 3125        // prompt tiles (64 rows each)
#define PGRID 512         // persistent blocks for k_gemm_p

using u16 = unsigned short;
typedef __attribute__((ext_vector_type(8))) short short8;
typedef __attribute__((ext_vector_type(4))) float f32x4;

__device__ __forceinline__ float b2f(u16 u) {
    union { unsigned int i; float f; } v; v.i = ((unsigned int)u) << 16; return v.f;
}
__device__ __forceinline__ u16 f2b(float f) {  // round-to-nearest-even
    union { float f; unsigned int i; } v; v.f = f;
    return (u16)((v.i + 0x7fffu + ((v.i >> 16) & 1u)) >> 16);
}
__device__ __forceinline__ void split2(float f, u16& h, u16& l) {
    h = f2b(f);
    l = f2b(f - b2f(h));
}

// --- prep: misc (blocks 0..63) + XCD-partitioned count/rank (blocks 64+) ---
__global__ __launch_bounds__(256) void k_prep(
    const unsigned* mask, int* flag,
    const float* w_pin, const float* w_pout, u16* WTph, u16* WTpl,
    const float* ws0, const float* wn0, u16* WT0h, u16* WT0l,
    const float* ws1, const float* wn1, u16* WT1h, u16* WT1l,
    const float* bc, float* outp,
    const int* __restrict__ dst0, const int* __restrict__ dst1,
    int* cnt0, int* cnt1, int* rk0, int* rk1) {
    const int bid = blockIdx.x;
    const int t = threadIdx.x;
    if (bid < 64) {
        // misc: detect + prompt WT + layer0/1 WT splits + out-bias init
        const int R0 = 50000;             // detect words
        const int R1 = R0 + 128 * 128;    // prompt WT
        const int R2 = R1 + 256 * 384;    // layer0 WT
        const int R3 = R2 + 256 * 512;    // layer1 WT
        const int R4 = R3 + 2 * N2v;      // out bias init
        for (int i = bid * 256 + t; i < R4; i += 64 * 256) {
            if (i < R0) {
                if (mask[i] > 1u) atomicOr(flag, 1);
            } else if (i < R1) {
                int j = i - R0, n = j >> 7, k = j & 127;
                float f = (n < 64) ? w_pin[k * 64 + n] : w_pout[k * 64 + (n - 64)];
                split2(f, WTph[j], WTpl[j]);
            } else if (i < R2) {
                int j = i - R1, n = j / 384, k = j % 384;
                float f = (k < 192) ? ws0[k * 256 + n] : wn0[(k - 192) * 256 + n];
                split2(f, WT0h[j], WT0l[j]);
            } else if (i < R3) {
                int j = i - R2, n = j >> 9, k = j & 511;
                float f = (k < 256) ? ws1[k * 256 + n] : wn1[(k - 256) * 256 + n];
                split2(f, WT1h[j], WT1l[j]);
            } else {
                int j = i - R3;
                outp[j] = bc[j & 1];
            }
        }
        return;
    }
    // partitioned count+rank: partition p only atomics its own dst range
    const int part = (bid - 64) & 7;           // == bid%8 -> XCD-local
    const int chunk = (bid - 64) >> 3;
    const int nch = (gridDim.x - 64) >> 3;
    {
        const int per = (E0v + nch - 1) / nch;
        const int i1 = min((chunk + 1) * per, E0v);
        for (int i = chunk * per + t; i < i1; i += 256) {
            int d = dst0[i];
            if (d / 6250 == part) rk0[i] = atomicAdd(&cnt0[d], 1);
        }
    }
    {
        const int per = (E1v + nch - 1) / nch;
        const int i1 = min((chunk + 1) * per, E1v);
        for (int i = chunk * per + t; i < i1; i += 256) {
            int d = dst1[i];
            if (d / 1250 == part) rk1[i] = atomicAdd(&cnt1[d], 1);
        }
    }
}

// --- hierarchical scan, pass A: per-tile local exclusive scan + tile sums --
__global__ __launch_bounds__(256) void k_scan_a(const int* __restrict__ cnt0,
                                                int* __restrict__ off0,
                                                const int* __restrict__ cnt1,
                                                int* __restrict__ off1,
                                                int* __restrict__ tsum) {
    __shared__ int sd[256];
    const int t = threadIdx.x;
    const int blk = blockIdx.x;
    const int g1 = (blk >= TB0);
    const int b = g1 ? blk - TB0 : blk;
    const int n = g1 ? N2v : N1v;
    const int* cnt = g1 ? cnt1 : cnt0;
    int* off = g1 ? off1 : off0;
    const int i0 = b * 1024 + t * 4;
    int c[4] = {0, 0, 0, 0};
    if (i0 + 3 < n) {
        *(int4*)c = *(const int4*)&cnt[i0];
    } else {
        for (int j = 0; j < 4; j++) if (i0 + j < n) c[j] = cnt[i0 + j];
    }
    int s = c[0] + c[1] + c[2] + c[3];
    sd[t] = s;
    __syncthreads();
#pragma unroll
    for (int d = 1; d < 256; d <<= 1) {
        int v = (t >= d) ? sd[t - d] : 0;
        __syncthreads();
        sd[t] += v;
        __syncthreads();
    }
    int run = sd[t] - s;  // exclusive prefix within tile
    int o4[4];
#pragma unroll
    for (int j = 0; j < 4; j++) { o4[j] = run; run += c[j]; }
    if (i0 + 3 < n) *(int4*)&off[i0] = *(const int4*)o4;
    else for (int j = 0; j < 4; j++) if (i0 + j < n) off[i0 + j] = o4[j];
    if (t == 255) tsum[blk] = sd[255];
}

// --- hierarchical scan, pass C: add tile bases (segmented), sentinels ------
__global__ __launch_bounds__(256) void k_scan_c(int* __restrict__ off0,
                                                int* __restrict__ off1,
                                                const int* __restrict__ tsum) {
    __shared__ int lbase;
    const int t = threadIdx.x;
    const int blk = blockIdx.x;
    const int g1 = (blk >= TB0);
    const int b = g1 ? blk - TB0 : blk;
    const int n = g1 ? N2v : N1v;
    int* off = g1 ? off1 : off0;
    if (t < 64) {
        int v = (t < TBL) ? tsum[t] : 0;
        int incl = v;
#pragma unroll
        for (int d = 1; d < 64; d <<= 1) {
            int u = __shfl_up(incl, d);
            if (t >= d) incl += u;
        }
        int total0 = __shfl(incl, TB0 - 1);      // sum of graph-0 tiles
        if (t == blk) lbase = (incl - v) - (g1 ? total0 : 0);
    }
    __syncthreads();
    const int base = lbase;
    const int i0 = b * 1024 + t * 4;
    if (i0 + 3 < n) {
        int4 v = *(int4*)&off[i0];
        v.x += base; v.y += base; v.z += base; v.w += base;
        *(int4*)&off[i0] = v;
    } else {
        for (int j = 0; j < 4; j++) if (i0 + j < n) off[i0 + j] += base;
    }
    if (blk == 0 && t == 0) { off0[N1v] = E0v; off1[N2v] = E1v; }
}

// --- scatter, atomic-free, 8-way dst-partitioned (XCD write locality) ------
__global__ __launch_bounds__(256) void k_scatter2(
    const int* __restrict__ src0, const int* __restrict__ dst0,
    const int* __restrict__ off0, const int* __restrict__ rk0, int* __restrict__ ei0,
    const int* __restrict__ src1, const int* __restrict__ dst1,
    const int* __restrict__ off1, const int* __restrict__ rk1, int* __restrict__ ei1) {
    const int part = blockIdx.x & 7;
    const int chunk = blockIdx.x >> 3;
    const int nch = gridDim.x >> 3;
    {
        const int per = (E0v + nch - 1) / nch;
        const int i1 = min((chunk + 1) * per, E0v);
        for (int i = chunk * per + (int)threadIdx.x; i < i1; i += 256) {
            int d = dst0[i];
            if (d / 6250 == part) ei0[off0[d] + rk0[i]] = src0[i];
        }
    }
    {
        const int per = (E1v + nch - 1) / nch;
        const int i1 = min((chunk + 1) * per, E1v);
        for (int i = chunk * per + (int)threadIdx.x; i < i1; i += 256) {
            int d = dst1[i];
            if (d / 1250 == part) ei1[off1[d] + rk1[i]] = src1[i];
        }
    }
}

// ---------------------------------------------------------------------------
// Prompt GEMM, persistent pipelined (frozen R6 form).
// ---------------------------------------------------------------------------
__global__ __launch_bounds__(256, 2) void k_gemm_p(
    const float* __restrict__ A, const u16* __restrict__ Bh, const u16* __restrict__ Bl,
    const float* __restrict__ b_pin, const float* __restrict__ b_pout,
    const void* maskp, const int* __restrict__ flag, u16* __restrict__ G) {
    __shared__ __align__(16) u16 STG[2][8448];  // 16 frags x 66 grp x 8
    __shared__ __align__(16) u16 EPI[8704];     // 64 x 136
    const int t = threadIdx.x;
    const int lane = t & 63, w = t >> 6;
    const int m = lane & 15, q = lane >> 4;
    const int colbase = w * 32;
    const int r15 = t >> 4, ch = t & 15;
    const int k0s = ch >> 2, q2s = ch & 3;

    const size_t ba = (size_t)(colbase + m) * 128 + q * 8;
    const size_t bb = (size_t)(colbase + 16 + m) * 128 + q * 8;
    short8 BfA[4][2], BfB[4][2];
#pragma unroll
    for (int k0 = 0; k0 < 4; k0++) {
        BfA[k0][0] = *(const short8*)&Bh[ba + k0 * 32];
        BfA[k0][1] = *(const short8*)&Bl[ba + k0 * 32];
        BfB[k0][0] = *(const short8*)&Bh[bb + k0 * 32];
        BfB[k0][1] = *(const short8*)&Bl[bb + k0 * 32];
    }
    const int fl = *flag;
    float bv0, bv1;
    {
        int c0 = colbase + m, c1 = colbase + 16 + m;
        bv0 = (c0 < 64) ? b_pin[c0] : b_pout[c0 - 64];
        bv1 = (c1 < 64) ? b_pin[c1] : b_pout[c1 - 64];
    }

    float4 va[8];
    {
        const float* ap = &A[(size_t)(blockIdx.x * 64 + r15) * 128 + ch * 8];
#pragma unroll
        for (int p = 0; p < 4; p++) {
            va[2 * p]     = *(const float4*)(ap + (size_t)p * 16 * 128);
            va[2 * p + 1] = *(const float4*)(ap + (size_t)p * 16 * 128 + 4);
        }
    }

    int buf = 0;
    for (int bm = blockIdx.x; bm < NTILE; bm += PGRID, buf ^= 1) {
        const int r0 = bm * 64;
        u16* stg = STG[buf];
#pragma unroll
        for (int p = 0; p < 4; p++) {
            u16 h8[8];
            h8[0] = f2b(va[2 * p].x); h8[1] = f2b(va[2 * p].y);
            h8[2] = f2b(va[2 * p].z); h8[3] = f2b(va[2 * p].w);
            h8[4] = f2b(va[2 * p + 1].x); h8[5] = f2b(va[2 * p + 1].y);
            h8[6] = f2b(va[2 * p + 1].z); h8[7] = f2b(va[2 * p + 1].w);
            *(uint4*)&stg[((p * 4 + k0s) * 66 + 16 * q2s + r15) * 8] = *(const uint4*)h8;
        }
        __syncthreads();   // B1: staging visible

        if (bm + PGRID < NTILE) {
            const float* ap = &A[(size_t)((bm + PGRID) * 64 + r15) * 128 + ch * 8];
#pragma unroll
            for (int p = 0; p < 4; p++) {
                va[2 * p]     = *(const float4*)(ap + (size_t)p * 16 * 128);
                va[2 * p + 1] = *(const float4*)(ap + (size_t)p * 16 * 128 + 4);
            }
        }
        bool mk0, mk1;
        {
            const int ra = r0 + (t >> 3), rb = ra + 32;
            if (fl) {
                mk0 = ((const unsigned char*)maskp)[ra] != 0;
                mk1 = ((const unsigned char*)maskp)[rb] != 0;
            } else {
                mk0 = ((const int*)maskp)[ra] != 0;
                mk1 = ((const int*)maskp)[rb] != 0;
            }
        }

        f32x4 acc[4][2] = {};
#pragma unroll
        for (int k0 = 0; k0 < 4; k0++) {
#pragma unroll
            for (int mi = 0; mi < 4; mi++) {
                short8 af = *(const short8*)&stg[((mi * 4 + k0) * 66 + lane) * 8];
                acc[mi][0] = __builtin_amdgcn_mfma_f32_16x16x32_bf16(af, BfA[k0][0], acc[mi][0], 0, 0, 0);
                acc[mi][0] = __builtin_amdgcn_mfma_f32_16x16x32_bf16(af, BfA[k0][1], acc[mi][0], 0, 0, 0);
                acc[mi][1] = __builtin_amdgcn_mfma_f32_16x16x32_bf16(af, BfB[k0][0], acc[mi][1], 0, 0, 0);
                acc[mi][1] = __builtin_amdgcn_mfma_f32_16x16x32_bf16(af, BfB[k0][1], acc[mi][1], 0, 0, 0);
            }
        }

#pragma unroll
        for (int mi = 0; mi < 4; mi++)
#pragma unroll
            for (int r = 0; r < 4; r++) {
                float v0 = acc[mi][0][r] + bv0;
                float v1 = acc[mi][1][r] + bv1;
                v0 = v0 > 0.f ? v0 : 0.f;
                v1 = v1 > 0.f ? v1 : 0.f;
                EPI[(mi * 16 + q * 4 + r) * 136 + colbase + m] = f2b(v0);
                EPI[(mi * 16 + q * 4 + r) * 136 + colbase + 16 + m] = f2b(v1);
            }
        __syncthreads();   // B2: EPI visible

        {
            const int c8 = t & 7;
            const int rt = t >> 3;
            *(uint4*)&G[(size_t)(r0 + rt) * 192 + 128 + c8 * 8] =
                *(const uint4*)&EPI[rt * 136 + (mk0 ? 0 : 64) + c8 * 8];
            *(uint4*)&G[(size_t)(r0 + 32 + rt) * 192 + 128 + c8 * 8] =
                *(const uint4*)&EPI[(32 + rt) * 136 + (mk1 ? 0 : 64) + c8 * 8];
        }
#pragma unroll
        for (int p = 0; p < 4; p++) {
            uint4 v = *(const uint4*)&stg[((p * 4 + k0s) * 66 + 16 * q2s + r15) * 8];
            *(uint4*)&G[(size_t)(r0 + r15 + 16 * p) * 192 + ch * 8] = v;
        }
    }
}

// ---------------------------------------------------------------------------
// Direct GEMM: MT rows x 128 cols/block, grid nbm*2 (bn=bid&1), N-out=256.
// Whole-K A in LDS once, ONE barrier, k0-grouped B. MODE 1: relu -> bf16
// CH. MODE 3: fused classifier -> atomic out.
// ---------------------------------------------------------------------------
template <int MODE, int KT, int SEGA0, int MT>
__global__ __launch_bounds__(256, 3) void k_g(
    const u16* __restrict__ A0, int s0, const u16* __restrict__ A1, int s1,
    const u16* __restrict__ Bh, const u16* __restrict__ Bl,
    const float* __restrict__ bias,
    u16* __restrict__ CH, float* __restrict__ outp, const float* __restrict__ wc,
    int M) {
    constexpr int MI = MT / 16;
    __shared__ __align__(16) u16 LA[MI * KT * 66 * 8];
    const int t = threadIdx.x;
    const int bm = blockIdx.x >> 1, bn = blockIdx.x & 1;
    const int lane = t & 63, w = t >> 6;
    const int m = lane & 15, q = lane >> 4;
    const int r0 = bm * MT;
    const int colbase = bn * 128 + w * 32;
    const int K = KT * 32;

    // stage whole-K A-tile (frag stride 66 -> uniform banks)
    {
        constexpr int TPR = 256 / MT;
        constexpr int SPT = KT / TPR;
        const int rr = t / TPR, sub = t & (TPR - 1);
        int arow = r0 + rr; if (arow >= M) arow = M - 1;
        const int mi = rr >> 4, r15 = rr & 15;
#pragma unroll
        for (int s = 0; s < SPT; s++) {
            const int kc = sub * SPT + s;
#pragma unroll
            for (int q2 = 0; q2 < 4; q2++) {
                const int c = kc * 32 + q2 * 8;
                uint4 v = (c < SEGA0)
                              ? *(const uint4*)&A0[(size_t)arow * s0 + c]
                              : *(const uint4*)&A1[(size_t)arow * s1 + (c - SEGA0)];
                *(uint4*)&LA[((mi * KT + kc) * 66 + 16 * q2 + r15) * 8] = v;
            }
        }
    }
    __syncthreads();

    const size_t ba = (size_t)(colbase + m) * K + q * 8;
    const size_t bb = (size_t)(colbase + 16 + m) * K + q * 8;

    f32x4 acc[MI][2] = {};
#pragma unroll 1
    for (int kb = 0; kb < KT; kb += 4) {
#pragma unroll
        for (int k0 = 0; k0 < 4; k0++) {
            const size_t ko = (size_t)(kb + k0) * 32;
            short8 b0h = *(const short8*)&Bh[ba + ko];
            short8 b0l = *(const short8*)&Bl[ba + ko];
            short8 b1h = *(const short8*)&Bh[bb + ko];
            short8 b1l = *(const short8*)&Bl[bb + ko];
#pragma unroll
            for (int mi = 0; mi < MI; mi++) {
                short8 af = *(const short8*)&LA[((mi * KT + kb + k0) * 66 + lane) * 8];
                acc[mi][0] = __builtin_amdgcn_mfma_f32_16x16x32_bf16(af, b0h, acc[mi][0], 0, 0, 0);
                acc[mi][0] = __builtin_amdgcn_mfma_f32_16x16x32_bf16(af, b0l, acc[mi][0], 0, 0, 0);
                acc[mi][1] = __builtin_amdgcn_mfma_f32_16x16x32_bf16(af, b1h, acc[mi][1], 0, 0, 0);
                acc[mi][1] = __builtin_amdgcn_mfma_f32_16x16x32_bf16(af, b1l, acc[mi][1], 0, 0, 0);
            }
        }
    }

    if (MODE == 1) {
        float bv[2];
#pragma unroll
        for (int nt = 0; nt < 2; nt++) bv[nt] = bias[colbase + nt * 16 + m];
        __syncthreads();
#pragma unroll
        for (int mi = 0; mi < MI; mi++)
#pragma unroll
            for (int nt = 0; nt < 2; nt++)
#pragma unroll
                for (int r = 0; r < 4; r++) {
                    float v = acc[mi][nt][r] + bv[nt];
                    v = v > 0.f ? v : 0.f;
                    LA[(mi * 16 + q * 4 + r) * 136 + w * 32 + nt * 16 + m] = f2b(v);
                }
        __syncthreads();
        const int c16 = t & 15;
#pragma unroll
        for (int pass = 0; pass < MT / 16; pass++) {
            const int rt = pass * 16 + (t >> 4);
            const int row = r0 + rt;
            if (row < M) {
                *(uint4*)&CH[(size_t)row * 256 + bn * 128 + c16 * 8] =
                    *(const uint4*)&LA[rt * 136 + c16 * 8];
            }
        }
    } else {
        const int ca = colbase + m, cb = colbase + 16 + m;
        const float bva = bias[ca], bvb = bias[cb];
        const float w0a = wc[ca * 2], w1a = wc[ca * 2 + 1];
        const float w0b = wc[cb * 2], w1b = wc[cb * 2 + 1];
#pragma unroll
        for (int mi = 0; mi < MI; mi++) {
#pragma unroll
            for (int r = 0; r < 4; r++) {
                int row = r0 + mi * 16 + q * 4 + r;
                float va = acc[mi][0][r] + bva;
                float vb = acc[mi][1][r] + bvb;
                float p0 = va * w0a + vb * w0b;
                float p1 = va * w1a + vb * w1b;
#pragma unroll
                for (int s = 1; s < 16; s <<= 1) {
                    p0 += __shfl_xor(p0, s);
                    p1 += __shfl_xor(p1, s);
                }
                if (m == 0 && row < M) {
                    atomicAdd(&outp[row * 2], p0);
                    atomicAdd(&outp[row * 2 + 1], p1);
                }
            }
        }
    }
}

// --- layer-0 mean-agg: wave/dst over G rows (384B), 4-edge pipelined -------
__global__ void k_agg0(const u16* __restrict__ G, const int* __restrict__ off,
                       const int* __restrict__ eidx, u16* __restrict__ aggH) {
    int wid = (blockIdx.x * blockDim.x + threadIdx.x) >> 6;
    int lane = threadIdx.x & 63;
    if (wid >= N1v) return;
    int b = off[wid], e = off[wid + 1];
    float f0 = 0.f, f1 = 0.f, p0 = 0.f;
    for (int base = b; base < e; base += 64) {
        int li = base + lane;
        int idx = eidx[li < e ? li : (e - 1)];
        int nch = e - base; if (nch > 64) nch = 64;
        int j = 0;
        for (; j + 4 <= nch; j += 4) {
            int sa = __shfl(idx, j), sb = __shfl(idx, j + 1);
            int sc = __shfl(idx, j + 2), sd = __shfl(idx, j + 3);
            const u16* ra = &G[(size_t)sa * 192];
            const u16* rb = &G[(size_t)sb * 192];
            const u16* rc = &G[(size_t)sc * 192];
            const u16* rd = &G[(size_t)sd * 192];
            unsigned fa = *(const unsigned*)&ra[2 * lane];
            unsigned fb = *(const unsigned*)&rb[2 * lane];
            unsigned fc = *(const unsigned*)&rc[2 * lane];
            unsigned fd = *(const unsigned*)&rd[2 * lane];
            u16 pa = ra[128 + lane], pb = rb[128 + lane];
            u16 pc = rc[128 + lane], pd = rd[128 + lane];
            f0 += b2f((u16)fa) + b2f((u16)fb) + b2f((u16)fc) + b2f((u16)fd);
            f1 += b2f((u16)(fa >> 16)) + b2f((u16)(fb >> 16)) +
                  b2f((u16)(fc >> 16)) + b2f((u16)(fd >> 16));
            p0 += b2f(pa) + b2f(pb) + b2f(pc) + b2f(pd);
        }
        for (; j < nch; j++) {
            int s = __shfl(idx, j);
            const u16* row = &G[(size_t)s * 192];
            unsigned fv = *(const unsigned*)&row[2 * lane];
            f0 += b2f((u16)fv);
            f1 += b2f((u16)(fv >> 16));
            p0 += b2f(row[128 + lane]);
        }
    }
    int deg = e - b;
    float inv = 1.0f / (float)(deg > 1 ? deg : 1);
    size_t rb2 = (size_t)wid * 192;
    *(unsigned*)&aggH[rb2 + 2 * lane] =
        (unsigned)f2b(f0 * inv) | ((unsigned)f2b(f1 * inv) << 16);
    aggH[rb2 + 128 + lane] = f2b(p0 * inv);
}

// --- layer-1 mean-agg: wave/dst over h1H rows (512B), 4-edge pipelined -----
__global__ void k_agg1(const u16* __restrict__ h1H, const int* __restrict__ off,
                       const int* __restrict__ eidx, u16* __restrict__ aggH) {
    int wid = (blockIdx.x * blockDim.x + threadIdx.x) >> 6;
    int lane = threadIdx.x & 63;
    if (wid >= N2v) return;
    int b = off[wid], e = off[wid + 1];
    float a0 = 0.f, a1 = 0.f, a2 = 0.f, a3 = 0.f;
    for (int base = b; base < e; base += 64) {
        int li = base + lane;
        int idx = eidx[li < e ? li : (e - 1)];
        int nch = e - base; if (nch > 64) nch = 64;
        int j = 0;
        for (; j + 4 <= nch; j += 4) {
            int sa = __shfl(idx, j), sb = __shfl(idx, j + 1);
            int sc = __shfl(idx, j + 2), sd = __shfl(idx, j + 3);
            const u16* ra = &h1H[(size_t)sa * 256];
            const u16* rb = &h1H[(size_t)sb * 256];
            const u16* rc = &h1H[(size_t)sc * 256];
            const u16* rd = &h1H[(size_t)sd * 256];
            unsigned va0 = *(const unsigned*)&ra[2 * lane];
            unsigned vb0 = *(const unsigned*)&rb[2 * lane];
            unsigned vc0 = *(const unsigned*)&rc[2 * lane];
            unsigned vd0 = *(const unsigned*)&rd[2 * lane];
            unsigned va1 = *(const unsigned*)&ra[128 + 2 * lane];
            unsigned vb1 = *(const unsigned*)&rb[128 + 2 * lane];
            unsigned vc1 = *(const unsigned*)&rc[128 + 2 * lane];
            unsigned vd1 = *(const unsigned*)&rd[128 + 2 * lane];
            a0 += b2f((u16)va0) + b2f((u16)vb0) + b2f((u16)vc0) + b2f((u16)vd0);
            a1 += b2f((u16)(va0 >> 16)) + b2f((u16)(vb0 >> 16)) +
                  b2f((u16)(vc0 >> 16)) + b2f((u16)(vd0 >> 16));
            a2 += b2f((u16)va1) + b2f((u16)vb1) + b2f((u16)vc1) + b2f((u16)vd1);
            a3 += b2f((u16)(va1 >> 16)) + b2f((u16)(vb1 >> 16)) +
                  b2f((u16)(vc1 >> 16)) + b2f((u16)(vd1 >> 16));
        }
        for (; j < nch; j++) {
            int s = __shfl(idx, j);
            const u16* row = &h1H[(size_t)s * 256];
            unsigned v0 = *(const unsigned*)&row[2 * lane];
            unsigned v1 = *(const unsigned*)&row[128 + 2 * lane];
            a0 += b2f((u16)v0); a1 += b2f((u16)(v0 >> 16));
            a2 += b2f((u16)v1); a3 += b2f((u16)(v1 >> 16));
        }
    }
    int deg = e - b;
    float inv = 1.0f / (float)(deg > 1 ? deg : 1);
    size_t rb2 = (size_t)wid * 256;
    *(unsigned*)&aggH[rb2 + 2 * lane] =
        (unsigned)f2b(a0 * inv) | ((unsigned)f2b(a1 * inv) << 16);
    *(unsigned*)&aggH[rb2 + 128 + 2 * lane] =
        (unsigned)f2b(a2 * inv) | ((unsigned)f2b(a3 * inv) << 16);
}

extern "C" void kernel_launch(void* const* d_in, const int* in_sizes, int n_in,
                              void* d_out, int out_size, void* d_ws, size_t ws_size,
                              hipStream_t stream) {
    const float* features = (const float*)d_in[0];
    const void* maskp     = d_in[1];
    const int* src0       = (const int*)d_in[2];
    const int* dst0       = (const int*)d_in[3];
    const int* src1       = (const int*)d_in[4];
    const int* dst1       = (const int*)d_in[5];
    const float* w_pin    = (const float*)d_in[7];
    const float* b_pin    = (const float*)d_in[8];
    const float* w_pout   = (const float*)d_in[9];
    const float* b_pout   = (const float*)d_in[10];
    const float* w_self0  = (const float*)d_in[11];
    const float* w_neigh0 = (const float*)d_in[12];
    const float* b0       = (const float*)d_in[13];
    const float* w_self1  = (const float*)d_in[14];
    const float* w_neigh1 = (const float*)d_in[15];
    const float* b1       = (const float*)d_in[16];
    const float* w_cls    = (const float*)d_in[17];
    const float* b_cls    = (const float*)d_in[18];
    float* out = (float*)d_out;
    (void)in_sizes; (void)n_in; (void)out_size; (void)ws_size;

    char* ws = (char*)d_ws;
    size_t o = 0;
    auto alloc = [&](size_t bytes) { size_t r = o; o += (bytes + 255) & ~(size_t)255; return r; };
    // zeroed block (one memset)
    size_t o_flag = alloc(4);
    size_t o_cnt0 = alloc(N1v * 4);
    size_t o_cnt1 = alloc(N2v * 4);
    size_t zero_end = o;
    // rest
    size_t o_G    = alloc((size_t)N0v * 192 * 2);   // 76.8 MB
    size_t o_aggH = alloc((size_t)N1v * 192 * 2);
    size_t o_h1H  = alloc((size_t)N1v * 256 * 2);
    size_t o_ag1H = alloc((size_t)N2v * 256 * 2);
    size_t o_wtph = alloc(128 * 128 * 2), o_wtpl = alloc(128 * 128 * 2);
    size_t o_wt0h = alloc(256 * 384 * 2), o_wt0l = alloc(256 * 384 * 2);
    size_t o_wt1h = alloc(256 * 512 * 2), o_wt1l = alloc(256 * 512 * 2);
    size_t o_off0 = alloc((N1v + 1) * 4);
    size_t o_off1 = alloc((N2v + 1) * 4);
    size_t o_ei0  = alloc((size_t)E0v * 4);
    size_t o_ei1  = alloc((size_t)E1v * 4);
    size_t o_rk0  = alloc((size_t)E0v * 4);
    size_t o_rk1  = alloc((size_t)E1v * 4);
    size_t o_tsum = alloc(TBL * 4);

    int* flag = (int*)(ws + o_flag);
    int* cnt0 = (int*)(ws + o_cnt0);
    int* cnt1 = (int*)(ws + o_cnt1);
    u16* G     = (u16*)(ws + o_G);
    u16* aggH  = (u16*)(ws + o_aggH);
    u16* h1H   = (u16*)(ws + o_h1H);
    u16* ag1H  = (u16*)(ws + o_ag1H);
    u16* WTph = (u16*)(ws + o_wtph);
    u16* WTpl = (u16*)(ws + o_wtpl);
    u16* WT0h = (u16*)(ws + o_wt0h);
    u16* WT0l = (u16*)(ws + o_wt0l);
    u16* WT1h = (u16*)(ws + o_wt1h);
    u16* WT1l = (u16*)(ws + o_wt1l);
    int* off0 = (int*)(ws + o_off0);
    int* off1 = (int*)(ws + o_off1);
    int* ei0  = (int*)(ws + o_ei0);
    int* ei1  = (int*)(ws + o_ei1);
    int* rk0  = (int*)(ws + o_rk0);
    int* rk1  = (int*)(ws + o_rk1);
    int* tsum = (int*)(ws + o_tsum);

    // 1: zero flag + counters in one memset
    hipMemsetAsync(ws + o_flag, 0, zero_end - o_flag, stream);

    // 2: prep (misc blocks 0..63 + XCD-partitioned count/rank blocks 64+)
    k_prep<<<2112, 256, 0, stream>>>((const unsigned*)maskp, flag,
                                     w_pin, w_pout, WTph, WTpl,
                                     w_self0, w_neigh0, WT0h, WT0l,
                                     w_self1, w_neigh1, WT1h, WT1l,
                                     b_cls, out, dst0, dst1, cnt0, cnt1, rk0, rk1);

    // 3-4: hierarchical scan (both graphs)
    k_scan_a<<<TBL, 256, 0, stream>>>(cnt0, off0, cnt1, off1, tsum);
    k_scan_c<<<TBL, 256, 0, stream>>>(off0, off1, tsum);

    // 5: edge scatter (atomic-free, XCD-partitioned)
    k_scatter2<<<2048, 256, 0, stream>>>(src0, dst0, off0, rk0, ei0,
                                         src1, dst1, off1, rk1, ei1);

    // 6: prompt GEMM -> G[N0,192] = [featH | psel]  (persistent pipelined)
    k_gemm_p<<<PGRID, 256, 0, stream>>>(features, WTph, WTpl,
                                        b_pin, b_pout, maskp, flag, G);

    // 7: layer-0 mean agg -> aggH[N1,192]
    k_agg0<<<(N1v + 3) / 4, 256, 0, stream>>>(G, off0, ei0, aggH);

    // 8: h1 = relu([G | agg] @ WT0 + b0) -> h1H[N1,256]  (K=384, MT=64)
    k_g<1, 12, 192, 64><<<((N1v + 63) / 64) * 2, 256, 0, stream>>>(
        G, 192, aggH, 192, WT0h, WT0l, b0, h1H, nullptr, nullptr, N1v);

    // 9: layer-1 mean agg -> ag1H[N2,256]
    k_agg1<<<(N2v + 3) / 4, 256, 0, stream>>>(h1H, off1, ei1, ag1H);

    // 10: logits = ([h1|agg1] @ WT1 + b1) @ w_cls + b_cls  (fused, K=512, MT=32)
    k_g<3, 16, 256, 32><<<((N2v + 31) / 32) * 2, 256, 0, stream>>>(
        h1H, 256, ag1H, 256, WT1h, WT1l, b1, nullptr, out, w_cls, N2v);
}

// Round 10
// 410.966 us; speedup vs baseline: 1.0231x; 1.0231x over previous
//
#include <hip/hip_runtime.h>

// ---------------------------------------------------------------------------
// GNNWithPrompt, f32 I/O. Hi-only bf16 activations, hi+lo bf16 weights.
// R6 skeleton (best, 413us). Single change: k_g kb-loop unroll 1 -> 2 so
// next kb-pair's B loads pipeline under current MFMAs (L2 latency hiding).
// k_gemm_p: frozen R6 persistent pipelined form. Scatter: rank-in-prep
// (atomic-free) + 8-way XCD dst-partitioning.
// ---------------------------------------------------------------------------

#define N0v 200000
#define N1v 50000
#define N2v 10000
#define E0v 800000
#define E1v 160000
#define TB0 49            // graph0 scan tiles (1024 each)
#define TB1 10            // graph1 scan tiles
#define TBL (TB0 + TB1)
#define NTILE 3125        // prompt tiles (64 rows each)
#define PGRID 512         // persistent blocks for k_gemm_p

using u16 = unsigned short;
typedef __attribute__((ext_vector_type(8))) short short8;
typedef __attribute__((ext_vector_type(4))) float f32x4;

__device__ __forceinline__ float b2f(u16 u) {
    union { unsigned int i; float f; } v; v.i = ((unsigned int)u) << 16; return v.f;
}
__device__ __forceinline__ u16 f2b(float f) {  // round-to-nearest-even
    union { float f; unsigned int i; } v; v.f = f;
    return (u16)((v.i + 0x7fffu + ((v.i >> 16) & 1u)) >> 16);
}
__device__ __forceinline__ void split2(float f, u16& h, u16& l) {
    h = f2b(f);
    l = f2b(f - b2f(h));
}

// --- prep: detect + weight splits + out=bias init + degree counts + ranks --
__global__ void k_prep(const unsigned* mask, int* flag,
                       const float* w_pin, const float* w_pout, u16* WTph, u16* WTpl,
                       const float* ws0, const float* wn0, u16* WT0h, u16* WT0l,
                       const float* ws1, const float* wn1, u16* WT1h, u16* WT1l,
                       const float* bc, float* outp,
                       const int* __restrict__ dst0, const int* __restrict__ dst1,
                       int* cnt0, int* cnt1, int* rk0, int* rk1) {
    const int R0 = 50000;             // detect words
    const int R1 = R0 + 128 * 128;    // prompt WT
    const int R2 = R1 + 256 * 384;    // layer0 WT
    const int R3 = R2 + 256 * 512;    // layer1 WT
    const int R4 = R3 + 2 * N2v;      // out bias init
    const int R5 = R4 + E0v;          // count+rank graph 0
    const int R6 = R5 + E1v;          // count+rank graph 1
    for (int i = blockIdx.x * blockDim.x + threadIdx.x; i < R6;
         i += gridDim.x * blockDim.x) {
        if (i < R0) {
            if (mask[i] > 1u) atomicOr(flag, 1);
        } else if (i < R1) {
            int j = i - R0, n = j >> 7, k = j & 127;
            float f = (n < 64) ? w_pin[k * 64 + n] : w_pout[k * 64 + (n - 64)];
            split2(f, WTph[j], WTpl[j]);
        } else if (i < R2) {
            int j = i - R1, n = j / 384, k = j % 384;
            float f = (k < 192) ? ws0[k * 256 + n] : wn0[(k - 192) * 256 + n];
            split2(f, WT0h[j], WT0l[j]);
        } else if (i < R3) {
            int j = i - R2, n = j >> 9, k = j & 511;
            float f = (k < 256) ? ws1[k * 256 + n] : wn1[(k - 256) * 256 + n];
            split2(f, WT1h[j], WT1l[j]);
        } else if (i < R4) {
            int j = i - R3;
            outp[j] = bc[j & 1];
        } else if (i < R5) {
            int e = i - R4;
            rk0[e] = atomicAdd(&cnt0[dst0[e]], 1);
        } else {
            int e = i - R5;
            rk1[e] = atomicAdd(&cnt1[dst1[e]], 1);
        }
    }
}

// --- hierarchical scan, pass A: per-tile local exclusive scan + tile sums --
__global__ __launch_bounds__(256) void k_scan_a(const int* __restrict__ cnt0,
                                                int* __restrict__ off0,
                                                const int* __restrict__ cnt1,
                                                int* __restrict__ off1,
                                                int* __restrict__ tsum) {
    __shared__ int sd[256];
    const int t = threadIdx.x;
    const int blk = blockIdx.x;
    const int g1 = (blk >= TB0);
    const int b = g1 ? blk - TB0 : blk;
    const int n = g1 ? N2v : N1v;
    const int* cnt = g1 ? cnt1 : cnt0;
    int* off = g1 ? off1 : off0;
    const int i0 = b * 1024 + t * 4;
    int c[4] = {0, 0, 0, 0};
    if (i0 + 3 < n) {
        *(int4*)c = *(const int4*)&cnt[i0];
    } else {
        for (int j = 0; j < 4; j++) if (i0 + j < n) c[j] = cnt[i0 + j];
    }
    int s = c[0] + c[1] + c[2] + c[3];
    sd[t] = s;
    __syncthreads();
#pragma unroll
    for (int d = 1; d < 256; d <<= 1) {
        int v = (t >= d) ? sd[t - d] : 0;
        __syncthreads();
        sd[t] += v;
        __syncthreads();
    }
    int run = sd[t] - s;  // exclusive prefix within tile
    int o4[4];
#pragma unroll
    for (int j = 0; j < 4; j++) { o4[j] = run; run += c[j]; }
    if (i0 + 3 < n) *(int4*)&off[i0] = *(const int4*)o4;
    else for (int j = 0; j < 4; j++) if (i0 + j < n) off[i0 + j] = o4[j];
    if (t == 255) tsum[blk] = sd[255];
}

// --- hierarchical scan, pass C: add tile bases (segmented), sentinels ------
__global__ __launch_bounds__(256) void k_scan_c(int* __restrict__ off0,
                                                int* __restrict__ off1,
                                                const int* __restrict__ tsum) {
    __shared__ int lbase;
    const int t = threadIdx.x;
    const int blk = blockIdx.x;
    const int g1 = (blk >= TB0);
    const int b = g1 ? blk - TB0 : blk;
    const int n = g1 ? N2v : N1v;
    int* off = g1 ? off1 : off0;
    if (t < 64) {
        int v = (t < TBL) ? tsum[t] : 0;
        int incl = v;
#pragma unroll
        for (int d = 1; d < 64; d <<= 1) {
            int u = __shfl_up(incl, d);
            if (t >= d) incl += u;
        }
        int total0 = __shfl(incl, TB0 - 1);      // sum of graph-0 tiles
        if (t == blk) lbase = (incl - v) - (g1 ? total0 : 0);
    }
    __syncthreads();
    const int base = lbase;
    const int i0 = b * 1024 + t * 4;
    if (i0 + 3 < n) {
        int4 v = *(int4*)&off[i0];
        v.x += base; v.y += base; v.z += base; v.w += base;
        *(int4*)&off[i0] = v;
    } else {
        for (int j = 0; j < 4; j++) if (i0 + j < n) off[i0 + j] += base;
    }
    if (blk == 0 && t == 0) { off0[N1v] = E0v; off1[N2v] = E1v; }
}

// --- scatter, atomic-free, 8-way dst-partitioned (XCD write locality) ------
__global__ __launch_bounds__(256) void k_scatter2(
    const int* __restrict__ src0, const int* __restrict__ dst0,
    const int* __restrict__ off0, const int* __restrict__ rk0, int* __restrict__ ei0,
    const int* __restrict__ src1, const int* __restrict__ dst1,
    const int* __restrict__ off1, const int* __restrict__ rk1, int* __restrict__ ei1) {
    const int part = blockIdx.x & 7;
    const int chunk = blockIdx.x >> 3;
    const int nch = gridDim.x >> 3;
    {
        const int per = (E0v + nch - 1) / nch;
        const int i1 = min((chunk + 1) * per, E0v);
        for (int i = chunk * per + (int)threadIdx.x; i < i1; i += 256) {
            int d = dst0[i];
            if (d / 6250 == part) ei0[off0[d] + rk0[i]] = src0[i];
        }
    }
    {
        const int per = (E1v + nch - 1) / nch;
        const int i1 = min((chunk + 1) * per, E1v);
        for (int i = chunk * per + (int)threadIdx.x; i < i1; i += 256) {
            int d = dst1[i];
            if (d / 1250 == part) ei1[off1[d] + rk1[i]] = src1[i];
        }
    }
}

// ---------------------------------------------------------------------------
// Prompt GEMM, persistent pipelined (frozen R6 form).
// ---------------------------------------------------------------------------
__global__ __launch_bounds__(256, 2) void k_gemm_p(
    const float* __restrict__ A, const u16* __restrict__ Bh, const u16* __restrict__ Bl,
    const float* __restrict__ b_pin, const float* __restrict__ b_pout,
    const void* maskp, const int* __restrict__ flag, u16* __restrict__ G) {
    __shared__ __align__(16) u16 STG[2][8448];  // 16 frags x 66 grp x 8
    __shared__ __align__(16) u16 EPI[8704];     // 64 x 136
    const int t = threadIdx.x;
    const int lane = t & 63, w = t >> 6;
    const int m = lane & 15, q = lane >> 4;
    const int colbase = w * 32;
    const int r15 = t >> 4, ch = t & 15;
    const int k0s = ch >> 2, q2s = ch & 3;

    const size_t ba = (size_t)(colbase + m) * 128 + q * 8;
    const size_t bb = (size_t)(colbase + 16 + m) * 128 + q * 8;
    short8 BfA[4][2], BfB[4][2];
#pragma unroll
    for (int k0 = 0; k0 < 4; k0++) {
        BfA[k0][0] = *(const short8*)&Bh[ba + k0 * 32];
        BfA[k0][1] = *(const short8*)&Bl[ba + k0 * 32];
        BfB[k0][0] = *(const short8*)&Bh[bb + k0 * 32];
        BfB[k0][1] = *(const short8*)&Bl[bb + k0 * 32];
    }
    const int fl = *flag;
    float bv0, bv1;
    {
        int c0 = colbase + m, c1 = colbase + 16 + m;
        bv0 = (c0 < 64) ? b_pin[c0] : b_pout[c0 - 64];
        bv1 = (c1 < 64) ? b_pin[c1] : b_pout[c1 - 64];
    }

    float4 va[8];
    {
        const float* ap = &A[(size_t)(blockIdx.x * 64 + r15) * 128 + ch * 8];
#pragma unroll
        for (int p = 0; p < 4; p++) {
            va[2 * p]     = *(const float4*)(ap + (size_t)p * 16 * 128);
            va[2 * p + 1] = *(const float4*)(ap + (size_t)p * 16 * 128 + 4);
        }
    }

    int buf = 0;
    for (int bm = blockIdx.x; bm < NTILE; bm += PGRID, buf ^= 1) {
        const int r0 = bm * 64;
        u16* stg = STG[buf];
#pragma unroll
        for (int p = 0; p < 4; p++) {
            u16 h8[8];
            h8[0] = f2b(va[2 * p].x); h8[1] = f2b(va[2 * p].y);
            h8[2] = f2b(va[2 * p].z); h8[3] = f2b(va[2 * p].w);
            h8[4] = f2b(va[2 * p + 1].x); h8[5] = f2b(va[2 * p + 1].y);
            h8[6] = f2b(va[2 * p + 1].z); h8[7] = f2b(va[2 * p + 1].w);
            *(uint4*)&stg[((p * 4 + k0s) * 66 + 16 * q2s + r15) * 8] = *(const uint4*)h8;
        }
        __syncthreads();   // B1: staging visible

        if (bm + PGRID < NTILE) {
            const float* ap = &A[(size_t)((bm + PGRID) * 64 + r15) * 128 + ch * 8];
#pragma unroll
            for (int p = 0; p < 4; p++) {
                va[2 * p]     = *(const float4*)(ap + (size_t)p * 16 * 128);
                va[2 * p + 1] = *(const float4*)(ap + (size_t)p * 16 * 128 + 4);
            }
        }
        bool mk0, mk1;
        {
            const int ra = r0 + (t >> 3), rb = ra + 32;
            if (fl) {
                mk0 = ((const unsigned char*)maskp)[ra] != 0;
                mk1 = ((const unsigned char*)maskp)[rb] != 0;
            } else {
                mk0 = ((const int*)maskp)[ra] != 0;
                mk1 = ((const int*)maskp)[rb] != 0;
            }
        }

        f32x4 acc[4][2] = {};
#pragma unroll
        for (int k0 = 0; k0 < 4; k0++) {
#pragma unroll
            for (int mi = 0; mi < 4; mi++) {
                short8 af = *(const short8*)&stg[((mi * 4 + k0) * 66 + lane) * 8];
                acc[mi][0] = __builtin_amdgcn_mfma_f32_16x16x32_bf16(af, BfA[k0][0], acc[mi][0], 0, 0, 0);
                acc[mi][0] = __builtin_amdgcn_mfma_f32_16x16x32_bf16(af, BfA[k0][1], acc[mi][0], 0, 0, 0);
                acc[mi][1] = __builtin_amdgcn_mfma_f32_16x16x32_bf16(af, BfB[k0][0], acc[mi][1], 0, 0, 0);
                acc[mi][1] = __builtin_amdgcn_mfma_f32_16x16x32_bf16(af, BfB[k0][1], acc[mi][1], 0, 0, 0);
            }
        }

#pragma unroll
        for (int mi = 0; mi < 4; mi++)
#pragma unroll
            for (int r = 0; r < 4; r++) {
                float v0 = acc[mi][0][r] + bv0;
                float v1 = acc[mi][1][r] + bv1;
                v0 = v0 > 0.f ? v0 : 0.f;
                v1 = v1 > 0.f ? v1 : 0.f;
                EPI[(mi * 16 + q * 4 + r) * 136 + colbase + m] = f2b(v0);
                EPI[(mi * 16 + q * 4 + r) * 136 + colbase + 16 + m] = f2b(v1);
            }
        __syncthreads();   // B2: EPI visible

        {
            const int c8 = t & 7;
            const int rt = t >> 3;
            *(uint4*)&G[(size_t)(r0 + rt) * 192 + 128 + c8 * 8] =
                *(const uint4*)&EPI[rt * 136 + (mk0 ? 0 : 64) + c8 * 8];
            *(uint4*)&G[(size_t)(r0 + 32 + rt) * 192 + 128 + c8 * 8] =
                *(const uint4*)&EPI[(32 + rt) * 136 + (mk1 ? 0 : 64) + c8 * 8];
        }
#pragma unroll
        for (int p = 0; p < 4; p++) {
            uint4 v = *(const uint4*)&stg[((p * 4 + k0s) * 66 + 16 * q2s + r15) * 8];
            *(uint4*)&G[(size_t)(r0 + r15 + 16 * p) * 192 + ch * 8] = v;
        }
    }
}

// ---------------------------------------------------------------------------
// Direct GEMM: MT rows x 128 cols/block, grid nbm*2 (bn=bid&1), N-out=256.
// Whole-K A in LDS once, ONE barrier. kb-loop unroll 2: next kb-pair's B
// loads pipeline under current MFMAs (L2 latency hiding). MODE 1: relu ->
// bf16 CH. MODE 3: fused classifier -> atomic out.
// ---------------------------------------------------------------------------
template <int MODE, int KT, int SEGA0, int MT>
__global__ __launch_bounds__(256, 3) void k_g(
    const u16* __restrict__ A0, int s0, const u16* __restrict__ A1, int s1,
    const u16* __restrict__ Bh, const u16* __restrict__ Bl,
    const float* __restrict__ bias,
    u16* __restrict__ CH, float* __restrict__ outp, const float* __restrict__ wc,
    int M) {
    constexpr int MI = MT / 16;
    __shared__ __align__(16) u16 LA[MI * KT * 66 * 8];
    const int t = threadIdx.x;
    const int bm = blockIdx.x >> 1, bn = blockIdx.x & 1;
    const int lane = t & 63, w = t >> 6;
    const int m = lane & 15, q = lane >> 4;
    const int r0 = bm * MT;
    const int colbase = bn * 128 + w * 32;
    const int K = KT * 32;

    // stage whole-K A-tile (frag stride 66 -> uniform banks)
    {
        constexpr int TPR = 256 / MT;
        constexpr int SPT = KT / TPR;
        const int rr = t / TPR, sub = t & (TPR - 1);
        int arow = r0 + rr; if (arow >= M) arow = M - 1;
        const int mi = rr >> 4, r15 = rr & 15;
#pragma unroll
        for (int s = 0; s < SPT; s++) {
            const int kc = sub * SPT + s;
#pragma unroll
            for (int q2 = 0; q2 < 4; q2++) {
                const int c = kc * 32 + q2 * 8;
                uint4 v = (c < SEGA0)
                              ? *(const uint4*)&A0[(size_t)arow * s0 + c]
                              : *(const uint4*)&A1[(size_t)arow * s1 + (c - SEGA0)];
                *(uint4*)&LA[((mi * KT + kc) * 66 + 16 * q2 + r15) * 8] = v;
            }
        }
    }
    __syncthreads();

    const size_t ba = (size_t)(colbase + m) * K + q * 8;
    const size_t bb = (size_t)(colbase + 16 + m) * K + q * 8;

    f32x4 acc[MI][2] = {};
#pragma unroll 2
    for (int kb = 0; kb < KT; kb += 4) {
#pragma unroll
        for (int k0 = 0; k0 < 4; k0++) {
            const size_t ko = (size_t)(kb + k0) * 32;
            short8 b0h = *(const short8*)&Bh[ba + ko];
            short8 b0l = *(const short8*)&Bl[ba + ko];
            short8 b1h = *(const short8*)&Bh[bb + ko];
            short8 b1l = *(const short8*)&Bl[bb + ko];
#pragma unroll
            for (int mi = 0; mi < MI; mi++) {
                short8 af = *(const short8*)&LA[((mi * KT + kb + k0) * 66 + lane) * 8];
                acc[mi][0] = __builtin_amdgcn_mfma_f32_16x16x32_bf16(af, b0h, acc[mi][0], 0, 0, 0);
                acc[mi][0] = __builtin_amdgcn_mfma_f32_16x16x32_bf16(af, b0l, acc[mi][0], 0, 0, 0);
                acc[mi][1] = __builtin_amdgcn_mfma_f32_16x16x32_bf16(af, b1h, acc[mi][1], 0, 0, 0);
                acc[mi][1] = __builtin_amdgcn_mfma_f32_16x16x32_bf16(af, b1l, acc[mi][1], 0, 0, 0);
            }
        }
    }

    if (MODE == 1) {
        float bv[2];
#pragma unroll
        for (int nt = 0; nt < 2; nt++) bv[nt] = bias[colbase + nt * 16 + m];
        __syncthreads();
#pragma unroll
        for (int mi = 0; mi < MI; mi++)
#pragma unroll
            for (int nt = 0; nt < 2; nt++)
#pragma unroll
                for (int r = 0; r < 4; r++) {
                    float v = acc[mi][nt][r] + bv[nt];
                    v = v > 0.f ? v : 0.f;
                    LA[(mi * 16 + q * 4 + r) * 136 + w * 32 + nt * 16 + m] = f2b(v);
                }
        __syncthreads();
        const int c16 = t & 15;
#pragma unroll
        for (int pass = 0; pass < MT / 16; pass++) {
            const int rt = pass * 16 + (t >> 4);
            const int row = r0 + rt;
            if (row < M) {
                *(uint4*)&CH[(size_t)row * 256 + bn * 128 + c16 * 8] =
                    *(const uint4*)&LA[rt * 136 + c16 * 8];
            }
        }
    } else {
        const int ca = colbase + m, cb = colbase + 16 + m;
        const float bva = bias[ca], bvb = bias[cb];
        const float w0a = wc[ca * 2], w1a = wc[ca * 2 + 1];
        const float w0b = wc[cb * 2], w1b = wc[cb * 2 + 1];
#pragma unroll
        for (int mi = 0; mi < MI; mi++) {
#pragma unroll
            for (int r = 0; r < 4; r++) {
                int row = r0 + mi * 16 + q * 4 + r;
                float va = acc[mi][0][r] + bva;
                float vb = acc[mi][1][r] + bvb;
                float p0 = va * w0a + vb * w0b;
                float p1 = va * w1a + vb * w1b;
#pragma unroll
                for (int s = 1; s < 16; s <<= 1) {
                    p0 += __shfl_xor(p0, s);
                    p1 += __shfl_xor(p1, s);
                }
                if (m == 0 && row < M) {
                    atomicAdd(&outp[row * 2], p0);
                    atomicAdd(&outp[row * 2 + 1], p1);
                }
            }
        }
    }
}

// --- layer-0 mean-agg: wave/dst over G rows (384B), 4-edge pipelined -------
__global__ void k_agg0(const u16* __restrict__ G, const int* __restrict__ off,
                       const int* __restrict__ eidx, u16* __restrict__ aggH) {
    int wid = (blockIdx.x * blockDim.x + threadIdx.x) >> 6;
    int lane = threadIdx.x & 63;
    if (wid >= N1v) return;
    int b = off[wid], e = off[wid + 1];
    float f0 = 0.f, f1 = 0.f, p0 = 0.f;
    for (int base = b; base < e; base += 64) {
        int li = base + lane;
        int idx = eidx[li < e ? li : (e - 1)];
        int nch = e - base; if (nch > 64) nch = 64;
        int j = 0;
        for (; j + 4 <= nch; j += 4) {
            int sa = __shfl(idx, j), sb = __shfl(idx, j + 1);
            int sc = __shfl(idx, j + 2), sd = __shfl(idx, j + 3);
            const u16* ra = &G[(size_t)sa * 192];
            const u16* rb = &G[(size_t)sb * 192];
            const u16* rc = &G[(size_t)sc * 192];
            const u16* rd = &G[(size_t)sd * 192];
            unsigned fa = *(const unsigned*)&ra[2 * lane];
            unsigned fb = *(const unsigned*)&rb[2 * lane];
            unsigned fc = *(const unsigned*)&rc[2 * lane];
            unsigned fd = *(const unsigned*)&rd[2 * lane];
            u16 pa = ra[128 + lane], pb = rb[128 + lane];
            u16 pc = rc[128 + lane], pd = rd[128 + lane];
            f0 += b2f((u16)fa) + b2f((u16)fb) + b2f((u16)fc) + b2f((u16)fd);
            f1 += b2f((u16)(fa >> 16)) + b2f((u16)(fb >> 16)) +
                  b2f((u16)(fc >> 16)) + b2f((u16)(fd >> 16));
            p0 += b2f(pa) + b2f(pb) + b2f(pc) + b2f(pd);
        }
        for (; j < nch; j++) {
            int s = __shfl(idx, j);
            const u16* row = &G[(size_t)s * 192];
            unsigned fv = *(const unsigned*)&row[2 * lane];
            f0 += b2f((u16)fv);
            f1 += b2f((u16)(fv >> 16));
            p0 += b2f(row[128 + lane]);
        }
    }
    int deg = e - b;
    float inv = 1.0f / (float)(deg > 1 ? deg : 1);
    size_t rb2 = (size_t)wid * 192;
    *(unsigned*)&aggH[rb2 + 2 * lane] =
        (unsigned)f2b(f0 * inv) | ((unsigned)f2b(f1 * inv) << 16);
    aggH[rb2 + 128 + lane] = f2b(p0 * inv);
}

// --- layer-1 mean-agg: wave/dst over h1H rows (512B), 4-edge pipelined -----
__global__ void k_agg1(const u16* __restrict__ h1H, const int* __restrict__ off,
                       const int* __restrict__ eidx, u16* __restrict__ aggH) {
    int wid = (blockIdx.x * blockDim.x + threadIdx.x) >> 6;
    int lane = threadIdx.x & 63;
    if (wid >= N2v) return;
    int b = off[wid], e = off[wid + 1];
    float a0 = 0.f, a1 = 0.f, a2 = 0.f, a3 = 0.f;
    for (int base = b; base < e; base += 64) {
        int li = base + lane;
        int idx = eidx[li < e ? li : (e - 1)];
        int nch = e - base; if (nch > 64) nch = 64;
        int j = 0;
        for (; j + 4 <= nch; j += 4) {
            int sa = __shfl(idx, j), sb = __shfl(idx, j + 1);
            int sc = __shfl(idx, j + 2), sd = __shfl(idx, j + 3);
            const u16* ra = &h1H[(size_t)sa * 256];
            const u16* rb = &h1H[(size_t)sb * 256];
            const u16* rc = &h1H[(size_t)sc * 256];
            const u16* rd = &h1H[(size_t)sd * 256];
            unsigned va0 = *(const unsigned*)&ra[2 * lane];
            unsigned vb0 = *(const unsigned*)&rb[2 * lane];
            unsigned vc0 = *(const unsigned*)&rc[2 * lane];
            unsigned vd0 = *(const unsigned*)&rd[2 * lane];
            unsigned va1 = *(const unsigned*)&ra[128 + 2 * lane];
            unsigned vb1 = *(const unsigned*)&rb[128 + 2 * lane];
            unsigned vc1 = *(const unsigned*)&rc[128 + 2 * lane];
            unsigned vd1 = *(const unsigned*)&rd[128 + 2 * lane];
            a0 += b2f((u16)va0) + b2f((u16)vb0) + b2f((u16)vc0) + b2f((u16)vd0);
            a1 += b2f((u16)(va0 >> 16)) + b2f((u16)(vb0 >> 16)) +
                  b2f((u16)(vc0 >> 16)) + b2f((u16)(vd0 >> 16));
            a2 += b2f((u16)va1) + b2f((u16)vb1) + b2f((u16)vc1) + b2f((u16)vd1);
            a3 += b2f((u16)(va1 >> 16)) + b2f((u16)(vb1 >> 16)) +
                  b2f((u16)(vc1 >> 16)) + b2f((u16)(vd1 >> 16));
        }
        for (; j < nch; j++) {
            int s = __shfl(idx, j);
            const u16* row = &h1H[(size_t)s * 256];
            unsigned v0 = *(const unsigned*)&row[2 * lane];
            unsigned v1 = *(const unsigned*)&row[128 + 2 * lane];
            a0 += b2f((u16)v0); a1 += b2f((u16)(v0 >> 16));
            a2 += b2f((u16)v1); a3 += b2f((u16)(v1 >> 16));
        }
    }
    int deg = e - b;
    float inv = 1.0f / (float)(deg > 1 ? deg : 1);
    size_t rb2 = (size_t)wid * 256;
    *(unsigned*)&aggH[rb2 + 2 * lane] =
        (unsigned)f2b(a0 * inv) | ((unsigned)f2b(a1 * inv) << 16);
    *(unsigned*)&aggH[rb2 + 128 + 2 * lane] =
        (unsigned)f2b(a2 * inv) | ((unsigned)f2b(a3 * inv) << 16);
}

extern "C" void kernel_launch(void* const* d_in, const int* in_sizes, int n_in,
                              void* d_out, int out_size, void* d_ws, size_t ws_size,
                              hipStream_t stream) {
    const float* features = (const float*)d_in[0];
    const void* maskp     = d_in[1];
    const int* src0       = (const int*)d_in[2];
    const int* dst0       = (const int*)d_in[3];
    const int* src1       = (const int*)d_in[4];
    const int* dst1       = (const int*)d_in[5];
    const float* w_pin    = (const float*)d_in[7];
    const float* b_pin    = (const float*)d_in[8];
    const float* w_pout   = (const float*)d_in[9];
    const float* b_pout   = (const float*)d_in[10];
    const float* w_self0  = (const float*)d_in[11];
    const float* w_neigh0 = (const float*)d_in[12];
    const float* b0       = (const float*)d_in[13];
    const float* w_self1  = (const float*)d_in[14];
    const float* w_neigh1 = (const float*)d_in[15];
    const float* b1       = (const float*)d_in[16];
    const float* w_cls    = (const float*)d_in[17];
    const float* b_cls    = (const float*)d_in[18];
    float* out = (float*)d_out;
    (void)in_sizes; (void)n_in; (void)out_size; (void)ws_size;

    char* ws = (char*)d_ws;
    size_t o = 0;
    auto alloc = [&](size_t bytes) { size_t r = o; o += (bytes + 255) & ~(size_t)255; return r; };
    // zeroed block (one memset)
    size_t o_flag = alloc(4);
    size_t o_cnt0 = alloc(N1v * 4);
    size_t o_cnt1 = alloc(N2v * 4);
    size_t zero_end = o;
    // rest
    size_t o_G    = alloc((size_t)N0v * 192 * 2);   // 76.8 MB
    size_t o_aggH = alloc((size_t)N1v * 192 * 2);
    size_t o_h1H  = alloc((size_t)N1v * 256 * 2);
    size_t o_ag1H = alloc((size_t)N2v * 256 * 2);
    size_t o_wtph = alloc(128 * 128 * 2), o_wtpl = alloc(128 * 128 * 2);
    size_t o_wt0h = alloc(256 * 384 * 2), o_wt0l = alloc(256 * 384 * 2);
    size_t o_wt1h = alloc(256 * 512 * 2), o_wt1l = alloc(256 * 512 * 2);
    size_t o_off0 = alloc((N1v + 1) * 4);
    size_t o_off1 = alloc((N2v + 1) * 4);
    size_t o_ei0  = alloc((size_t)E0v * 4);
    size_t o_ei1  = alloc((size_t)E1v * 4);
    size_t o_rk0  = alloc((size_t)E0v * 4);
    size_t o_rk1  = alloc((size_t)E1v * 4);
    size_t o_tsum = alloc(TBL * 4);

    int* flag = (int*)(ws + o_flag);
    int* cnt0 = (int*)(ws + o_cnt0);
    int* cnt1 = (int*)(ws + o_cnt1);
    u16* G     = (u16*)(ws + o_G);
    u16* aggH  = (u16*)(ws + o_aggH);
    u16* h1H   = (u16*)(ws + o_h1H);
    u16* ag1H  = (u16*)(ws + o_ag1H);
    u16* WTph = (u16*)(ws + o_wtph);
    u16* WTpl = (u16*)(ws + o_wtpl);
    u16* WT0h = (u16*)(ws + o_wt0h);
    u16* WT0l = (u16*)(ws + o_wt0l);
    u16* WT1h = (u16*)(ws + o_wt1h);
    u16* WT1l = (u16*)(ws + o_wt1l);
    int* off0 = (int*)(ws + o_off0);
    int* off1 = (int*)(ws + o_off1);
    int* ei0  = (int*)(ws + o_ei0);
    int* ei1  = (int*)(ws + o_ei1);
    int* rk0  = (int*)(ws + o_rk0);
    int* rk1  = (int*)(ws + o_rk1);
    int* tsum = (int*)(ws + o_tsum);

    // 1: zero flag + counters in one memset
    hipMemsetAsync(ws + o_flag, 0, zero_end - o_flag, stream);

    // 2: prep (detect + weight splits + out init + degree counts + ranks)
    k_prep<<<1024, 256, 0, stream>>>((const unsigned*)maskp, flag,
                                     w_pin, w_pout, WTph, WTpl,
                                     w_self0, w_neigh0, WT0h, WT0l,
                                     w_self1, w_neigh1, WT1h, WT1l,
                                     b_cls, out, dst0, dst1, cnt0, cnt1, rk0, rk1);

    // 3-4: hierarchical scan (both graphs)
    k_scan_a<<<TBL, 256, 0, stream>>>(cnt0, off0, cnt1, off1, tsum);
    k_scan_c<<<TBL, 256, 0, stream>>>(off0, off1, tsum);

    // 5: edge scatter (atomic-free, XCD-partitioned)
    k_scatter2<<<2048, 256, 0, stream>>>(src0, dst0, off0, rk0, ei0,
                                         src1, dst1, off1, rk1, ei1);

    // 6: prompt GEMM -> G[N0,192] = [featH | psel]  (persistent pipelined)
    k_gemm_p<<<PGRID, 256, 0, stream>>>(features, WTph, WTpl,
                                        b_pin, b_pout, maskp, flag, G);

    // 7: layer-0 mean agg -> aggH[N1,192]
    k_agg0<<<(N1v + 3) / 4, 256, 0, stream>>>(G, off0, ei0, aggH);

    // 8: h1 = relu([G | agg] @ WT0 + b0) -> h1H[N1,256]  (K=384, MT=64)
    k_g<1, 12, 192, 64><<<((N1v + 63) / 64) * 2, 256, 0, stream>>>(
        G, 192, aggH, 192, WT0h, WT0l, b0, h1H, nullptr, nullptr, N1v);

    // 9: layer-1 mean agg -> ag1H[N2,256]
    k_agg1<<<(N2v + 3) / 4, 256, 0, stream>>>(h1H, off1, ei1, ag1H);

    // 10: logits = ([h1|agg1] @ WT1 + b1) @ w_cls + b_cls  (fused, K=512, MT=32)
    k_g<3, 16, 256, 32><<<((N2v + 31) / 32) * 2, 256, 0, stream>>>(
        h1H, 256, ag1H, 256, WT1h, WT1l, b1, nullptr, out, w_cls, N2v);
}

// Round 11
// 386.024 us; speedup vs baseline: 1.0892x; 1.0646x over previous
//
#include <hip/hip_runtime.h>

// ---------------------------------------------------------------------------
// GNNWithPrompt, f32 I/O. Hi-only bf16 activations, hi+lo bf16 weights.
// Count+rank (960K scattered atomics, ~40us standalone) FUSED into the
// latency-bound persistent prompt GEMM: each of 512 blocks owns 1875
// edges, one 256-edge slice per tile-iteration -> atomic latency hides in
// the GEMM's stall shadow. k_prep = misc only (~5us). k_g: kb-unroll 2.
// Scatter: rank-based (atomic-free) + 8-way XCD dst-partitioning.
// ---------------------------------------------------------------------------

#define N0v 200000
#define N1v 50000
#define N2v 10000
#define E0v 800000
#define E1v 160000
#define ETv (E0v + E1v)
#define TB0 49            // graph0 scan tiles (1024 each)
#define TB1 10            // graph1 scan tiles
#define TBL (TB0 + TB1)
#define NTILE 3125        // prompt tiles (64 rows each)
#define PGRID 512         // persistent blocks for k_gemm_p
#define EPB (ETv / PGRID) // 1875 edges per persistent block

using u16 = unsigned short;
typedef __attribute__((ext_vector_type(8))) short short8;
typedef __attribute__((ext_vector_type(4))) float f32x4;

__device__ __forceinline__ float b2f(u16 u) {
    union { unsigned int i; float f; } v; v.i = ((unsigned int)u) << 16; return v.f;
}
__device__ __forceinline__ u16 f2b(float f) {  // round-to-nearest-even
    union { float f; unsigned int i; } v; v.f = f;
    return (u16)((v.i + 0x7fffu + ((v.i >> 16) & 1u)) >> 16);
}
__device__ __forceinline__ void split2(float f, u16& h, u16& l) {
    h = f2b(f);
    l = f2b(f - b2f(h));
}

// --- prep: misc only (detect + weight splits + out=bias init) --------------
__global__ void k_prep(const unsigned* mask, int* flag,
                       const float* w_pin, const float* w_pout, u16* WTph, u16* WTpl,
                       const float* ws0, const float* wn0, u16* WT0h, u16* WT0l,
                       const float* ws1, const float* wn1, u16* WT1h, u16* WT1l,
                       const float* bc, float* outp) {
    const int R0 = 50000;             // detect words
    const int R1 = R0 + 128 * 128;    // prompt WT
    const int R2 = R1 + 256 * 384;    // layer0 WT
    const int R3 = R2 + 256 * 512;    // layer1 WT
    const int R4 = R3 + 2 * N2v;      // out bias init
    for (int i = blockIdx.x * blockDim.x + threadIdx.x; i < R4;
         i += gridDim.x * blockDim.x) {
        if (i < R0) {
            if (mask[i] > 1u) atomicOr(flag, 1);
        } else if (i < R1) {
            int j = i - R0, n = j >> 7, k = j & 127;
            float f = (n < 64) ? w_pin[k * 64 + n] : w_pout[k * 64 + (n - 64)];
            split2(f, WTph[j], WTpl[j]);
        } else if (i < R2) {
            int j = i - R1, n = j / 384, k = j % 384;
            float f = (k < 192) ? ws0[k * 256 + n] : wn0[(k - 192) * 256 + n];
            split2(f, WT0h[j], WT0l[j]);
        } else if (i < R3) {
            int j = i - R2, n = j >> 9, k = j & 511;
            float f = (k < 256) ? ws1[k * 256 + n] : wn1[(k - 256) * 256 + n];
            split2(f, WT1h[j], WT1l[j]);
        } else {
            int j = i - R3;
            outp[j] = bc[j & 1];
        }
    }
}

// --- hierarchical scan, pass A: per-tile local exclusive scan + tile sums --
__global__ __launch_bounds__(256) void k_scan_a(const int* __restrict__ cnt0,
                                                int* __restrict__ off0,
                                                const int* __restrict__ cnt1,
                                                int* __restrict__ off1,
                                                int* __restrict__ tsum) {
    __shared__ int sd[256];
    const int t = threadIdx.x;
    const int blk = blockIdx.x;
    const int g1 = (blk >= TB0);
    const int b = g1 ? blk - TB0 : blk;
    const int n = g1 ? N2v : N1v;
    const int* cnt = g1 ? cnt1 : cnt0;
    int* off = g1 ? off1 : off0;
    const int i0 = b * 1024 + t * 4;
    int c[4] = {0, 0, 0, 0};
    if (i0 + 3 < n) {
        *(int4*)c = *(const int4*)&cnt[i0];
    } else {
        for (int j = 0; j < 4; j++) if (i0 + j < n) c[j] = cnt[i0 + j];
    }
    int s = c[0] + c[1] + c[2] + c[3];
    sd[t] = s;
    __syncthreads();
#pragma unroll
    for (int d = 1; d < 256; d <<= 1) {
        int v = (t >= d) ? sd[t - d] : 0;
        __syncthreads();
        sd[t] += v;
        __syncthreads();
    }
    int run = sd[t] - s;  // exclusive prefix within tile
    int o4[4];
#pragma unroll
    for (int j = 0; j < 4; j++) { o4[j] = run; run += c[j]; }
    if (i0 + 3 < n) *(int4*)&off[i0] = *(const int4*)o4;
    else for (int j = 0; j < 4; j++) if (i0 + j < n) off[i0 + j] = o4[j];
    if (t == 255) tsum[blk] = sd[255];
}

// --- hierarchical scan, pass C: add tile bases (segmented), sentinels ------
__global__ __launch_bounds__(256) void k_scan_c(int* __restrict__ off0,
                                                int* __restrict__ off1,
                                                const int* __restrict__ tsum) {
    __shared__ int lbase;
    const int t = threadIdx.x;
    const int blk = blockIdx.x;
    const int g1 = (blk >= TB0);
    const int b = g1 ? blk - TB0 : blk;
    const int n = g1 ? N2v : N1v;
    int* off = g1 ? off1 : off0;
    if (t < 64) {
        int v = (t < TBL) ? tsum[t] : 0;
        int incl = v;
#pragma unroll
        for (int d = 1; d < 64; d <<= 1) {
            int u = __shfl_up(incl, d);
            if (t >= d) incl += u;
        }
        int total0 = __shfl(incl, TB0 - 1);      // sum of graph-0 tiles
        if (t == blk) lbase = (incl - v) - (g1 ? total0 : 0);
    }
    __syncthreads();
    const int base = lbase;
    const int i0 = b * 1024 + t * 4;
    if (i0 + 3 < n) {
        int4 v = *(int4*)&off[i0];
        v.x += base; v.y += base; v.z += base; v.w += base;
        *(int4*)&off[i0] = v;
    } else {
        for (int j = 0; j < 4; j++) if (i0 + j < n) off[i0 + j] += base;
    }
    if (blk == 0 && t == 0) { off0[N1v] = E0v; off1[N2v] = E1v; }
}

// --- scatter, atomic-free, 8-way dst-partitioned (XCD write locality) ------
__global__ __launch_bounds__(256) void k_scatter2(
    const int* __restrict__ src0, const int* __restrict__ dst0,
    const int* __restrict__ off0, const int* __restrict__ rk0, int* __restrict__ ei0,
    const int* __restrict__ src1, const int* __restrict__ dst1,
    const int* __restrict__ off1, const int* __restrict__ rk1, int* __restrict__ ei1) {
    const int part = blockIdx.x & 7;
    const int chunk = blockIdx.x >> 3;
    const int nch = gridDim.x >> 3;
    {
        const int per = (E0v + nch - 1) / nch;
        const int i1 = min((chunk + 1) * per, E0v);
        for (int i = chunk * per + (int)threadIdx.x; i < i1; i += 256) {
            int d = dst0[i];
            if (d / 6250 == part) ei0[off0[d] + rk0[i]] = src0[i];
        }
    }
    {
        const int per = (E1v + nch - 1) / nch;
        const int i1 = min((chunk + 1) * per, E1v);
        for (int i = chunk * per + (int)threadIdx.x; i < i1; i += 256) {
            int d = dst1[i];
            if (d / 1250 == part) ei1[off1[d] + rk1[i]] = src1[i];
        }
    }
}

// ---------------------------------------------------------------------------
// Prompt GEMM, persistent pipelined (R6 schedule) + FUSED count/rank:
// each block owns EPB edges; one 256-edge slice per tile-iteration issued
// right after the prefetch loads -> atomic latency hides under MFMA+
// epilogue. Remaining slices drained after the loop.
// ---------------------------------------------------------------------------
__global__ __launch_bounds__(256, 2) void k_gemm_p(
    const float* __restrict__ A, const u16* __restrict__ Bh, const u16* __restrict__ Bl,
    const float* __restrict__ b_pin, const float* __restrict__ b_pout,
    const void* maskp, const int* __restrict__ flag, u16* __restrict__ G,
    const int* __restrict__ dst0, const int* __restrict__ dst1,
    int* cnt0, int* cnt1, int* rk0, int* rk1) {
    __shared__ __align__(16) u16 STG[2][8448];  // 16 frags x 66 grp x 8
    __shared__ __align__(16) u16 EPI[8704];     // 64 x 136
    const int t = threadIdx.x;
    const int lane = t & 63, w = t >> 6;
    const int m = lane & 15, q = lane >> 4;
    const int colbase = w * 32;
    const int r15 = t >> 4, ch = t & 15;
    const int k0s = ch >> 2, q2s = ch & 3;

    // fused count/rank state: this block's edge range [eb0, eb1)
    const int eb0 = blockIdx.x * EPB;
    const int eb1 = eb0 + EPB;
    int esl = 0;                                  // next 256-edge slice
    auto do_edges = [&](int s) {
        int i = eb0 + s * 256 + t;
        if (i < eb1) {
            if (i < E0v) {
                rk0[i] = atomicAdd(&cnt0[dst0[i]], 1);
            } else {
                int e = i - E0v;
                rk1[e] = atomicAdd(&cnt1[dst1[e]], 1);
            }
        }
    };

    const size_t ba = (size_t)(colbase + m) * 128 + q * 8;
    const size_t bb = (size_t)(colbase + 16 + m) * 128 + q * 8;
    short8 BfA[4][2], BfB[4][2];
#pragma unroll
    for (int k0 = 0; k0 < 4; k0++) {
        BfA[k0][0] = *(const short8*)&Bh[ba + k0 * 32];
        BfA[k0][1] = *(const short8*)&Bl[ba + k0 * 32];
        BfB[k0][0] = *(const short8*)&Bh[bb + k0 * 32];
        BfB[k0][1] = *(const short8*)&Bl[bb + k0 * 32];
    }
    const int fl = *flag;
    float bv0, bv1;
    {
        int c0 = colbase + m, c1 = colbase + 16 + m;
        bv0 = (c0 < 64) ? b_pin[c0] : b_pout[c0 - 64];
        bv1 = (c1 < 64) ? b_pin[c1] : b_pout[c1 - 64];
    }

    float4 va[8];
    {
        const float* ap = &A[(size_t)(blockIdx.x * 64 + r15) * 128 + ch * 8];
#pragma unroll
        for (int p = 0; p < 4; p++) {
            va[2 * p]     = *(const float4*)(ap + (size_t)p * 16 * 128);
            va[2 * p + 1] = *(const float4*)(ap + (size_t)p * 16 * 128 + 4);
        }
    }

    int buf = 0;
    for (int bm = blockIdx.x; bm < NTILE; bm += PGRID, buf ^= 1) {
        const int r0 = bm * 64;
        u16* stg = STG[buf];
#pragma unroll
        for (int p = 0; p < 4; p++) {
            u16 h8[8];
            h8[0] = f2b(va[2 * p].x); h8[1] = f2b(va[2 * p].y);
            h8[2] = f2b(va[2 * p].z); h8[3] = f2b(va[2 * p].w);
            h8[4] = f2b(va[2 * p + 1].x); h8[5] = f2b(va[2 * p + 1].y);
            h8[6] = f2b(va[2 * p + 1].z); h8[7] = f2b(va[2 * p + 1].w);
            *(uint4*)&stg[((p * 4 + k0s) * 66 + 16 * q2s + r15) * 8] = *(const uint4*)h8;
        }
        __syncthreads();   // B1: staging visible

        if (bm + PGRID < NTILE) {
            const float* ap = &A[(size_t)((bm + PGRID) * 64 + r15) * 128 + ch * 8];
#pragma unroll
            for (int p = 0; p < 4; p++) {
                va[2 * p]     = *(const float4*)(ap + (size_t)p * 16 * 128);
                va[2 * p + 1] = *(const float4*)(ap + (size_t)p * 16 * 128 + 4);
            }
        }
        // fused edge slice: independent atomic traffic, hides under MFMA
        if (esl * 256 < EPB) { do_edges(esl); esl++; }

        bool mk0, mk1;
        {
            const int ra = r0 + (t >> 3), rb = ra + 32;
            if (fl) {
                mk0 = ((const unsigned char*)maskp)[ra] != 0;
                mk1 = ((const unsigned char*)maskp)[rb] != 0;
            } else {
                mk0 = ((const int*)maskp)[ra] != 0;
                mk1 = ((const int*)maskp)[rb] != 0;
            }
        }

        f32x4 acc[4][2] = {};
#pragma unroll
        for (int k0 = 0; k0 < 4; k0++) {
#pragma unroll
            for (int mi = 0; mi < 4; mi++) {
                short8 af = *(const short8*)&stg[((mi * 4 + k0) * 66 + lane) * 8];
                acc[mi][0] = __builtin_amdgcn_mfma_f32_16x16x32_bf16(af, BfA[k0][0], acc[mi][0], 0, 0, 0);
                acc[mi][0] = __builtin_amdgcn_mfma_f32_16x16x32_bf16(af, BfA[k0][1], acc[mi][0], 0, 0, 0);
                acc[mi][1] = __builtin_amdgcn_mfma_f32_16x16x32_bf16(af, BfB[k0][0], acc[mi][1], 0, 0, 0);
                acc[mi][1] = __builtin_amdgcn_mfma_f32_16x16x32_bf16(af, BfB[k0][1], acc[mi][1], 0, 0, 0);
            }
        }

#pragma unroll
        for (int mi = 0; mi < 4; mi++)
#pragma unroll
            for (int r = 0; r < 4; r++) {
                float v0 = acc[mi][0][r] + bv0;
                float v1 = acc[mi][1][r] + bv1;
                v0 = v0 > 0.f ? v0 : 0.f;
                v1 = v1 > 0.f ? v1 : 0.f;
                EPI[(mi * 16 + q * 4 + r) * 136 + colbase + m] = f2b(v0);
                EPI[(mi * 16 + q * 4 + r) * 136 + colbase + 16 + m] = f2b(v1);
            }
        __syncthreads();   // B2: EPI visible

        {
            const int c8 = t & 7;
            const int rt = t >> 3;
            *(uint4*)&G[(size_t)(r0 + rt) * 192 + 128 + c8 * 8] =
                *(const uint4*)&EPI[rt * 136 + (mk0 ? 0 : 64) + c8 * 8];
            *(uint4*)&G[(size_t)(r0 + 32 + rt) * 192 + 128 + c8 * 8] =
                *(const uint4*)&EPI[(32 + rt) * 136 + (mk1 ? 0 : 64) + c8 * 8];
        }
#pragma unroll
        for (int p = 0; p < 4; p++) {
            uint4 v = *(const uint4*)&stg[((p * 4 + k0s) * 66 + 16 * q2s + r15) * 8];
            *(uint4*)&G[(size_t)(r0 + r15 + 16 * p) * 192 + ch * 8] = v;
        }
    }
    // drain remaining edge slices
    while (esl * 256 < EPB) { do_edges(esl); esl++; }
}

// ---------------------------------------------------------------------------
// Direct GEMM: MT rows x 128 cols/block, grid nbm*2 (bn=bid&1), N-out=256.
// Whole-K A in LDS once, ONE barrier, kb-unroll 2 (B-load pipelining).
// MODE 1: relu -> bf16 CH. MODE 3: fused classifier -> atomic out.
// ---------------------------------------------------------------------------
template <int MODE, int KT, int SEGA0, int MT>
__global__ __launch_bounds__(256, 3) void k_g(
    const u16* __restrict__ A0, int s0, const u16* __restrict__ A1, int s1,
    const u16* __restrict__ Bh, const u16* __restrict__ Bl,
    const float* __restrict__ bias,
    u16* __restrict__ CH, float* __restrict__ outp, const float* __restrict__ wc,
    int M) {
    constexpr int MI = MT / 16;
    __shared__ __align__(16) u16 LA[MI * KT * 66 * 8];
    const int t = threadIdx.x;
    const int bm = blockIdx.x >> 1, bn = blockIdx.x & 1;
    const int lane = t & 63, w = t >> 6;
    const int m = lane & 15, q = lane >> 4;
    const int r0 = bm * MT;
    const int colbase = bn * 128 + w * 32;
    const int K = KT * 32;

    // stage whole-K A-tile (frag stride 66 -> uniform banks)
    {
        constexpr int TPR = 256 / MT;
        constexpr int SPT = KT / TPR;
        const int rr = t / TPR, sub = t & (TPR - 1);
        int arow = r0 + rr; if (arow >= M) arow = M - 1;
        const int mi = rr >> 4, r15 = rr & 15;
#pragma unroll
        for (int s = 0; s < SPT; s++) {
            const int kc = sub * SPT + s;
#pragma unroll
            for (int q2 = 0; q2 < 4; q2++) {
                const int c = kc * 32 + q2 * 8;
                uint4 v = (c < SEGA0)
                              ? *(const uint4*)&A0[(size_t)arow * s0 + c]
                              : *(const uint4*)&A1[(size_t)arow * s1 + (c - SEGA0)];
                *(uint4*)&LA[((mi * KT + kc) * 66 + 16 * q2 + r15) * 8] = v;
            }
        }
    }
    __syncthreads();

    const size_t ba = (size_t)(colbase + m) * K + q * 8;
    const size_t bb = (size_t)(colbase + 16 + m) * K + q * 8;

    f32x4 acc[MI][2] = {};
#pragma unroll 2
    for (int kb = 0; kb < KT; kb += 4) {
#pragma unroll
        for (int k0 = 0; k0 < 4; k0++) {
            const size_t ko = (size_t)(kb + k0) * 32;
            short8 b0h = *(const short8*)&Bh[ba + ko];
            short8 b0l = *(const short8*)&Bl[ba + ko];
            short8 b1h = *(const short8*)&Bh[bb + ko];
            short8 b1l = *(const short8*)&Bl[bb + ko];
#pragma unroll
            for (int mi = 0; mi < MI; mi++) {
                short8 af = *(const short8*)&LA[((mi * KT + kb + k0) * 66 + lane) * 8];
                acc[mi][0] = __builtin_amdgcn_mfma_f32_16x16x32_bf16(af, b0h, acc[mi][0], 0, 0, 0);
                acc[mi][0] = __builtin_amdgcn_mfma_f32_16x16x32_bf16(af, b0l, acc[mi][0], 0, 0, 0);
                acc[mi][1] = __builtin_amdgcn_mfma_f32_16x16x32_bf16(af, b1h, acc[mi][1], 0, 0, 0);
                acc[mi][1] = __builtin_amdgcn_mfma_f32_16x16x32_bf16(af, b1l, acc[mi][1], 0, 0, 0);
            }
        }
    }

    if (MODE == 1) {
        float bv[2];
#pragma unroll
        for (int nt = 0; nt < 2; nt++) bv[nt] = bias[colbase + nt * 16 + m];
        __syncthreads();
#pragma unroll
        for (int mi = 0; mi < MI; mi++)
#pragma unroll
            for (int nt = 0; nt < 2; nt++)
#pragma unroll
                for (int r = 0; r < 4; r++) {
                    float v = acc[mi][nt][r] + bv[nt];
                    v = v > 0.f ? v : 0.f;
                    LA[(mi * 16 + q * 4 + r) * 136 + w * 32 + nt * 16 + m] = f2b(v);
                }
        __syncthreads();
        const int c16 = t & 15;
#pragma unroll
        for (int pass = 0; pass < MT / 16; pass++) {
            const int rt = pass * 16 + (t >> 4);
            const int row = r0 + rt;
            if (row < M) {
                *(uint4*)&CH[(size_t)row * 256 + bn * 128 + c16 * 8] =
                    *(const uint4*)&LA[rt * 136 + c16 * 8];
            }
        }
    } else {
        const int ca = colbase + m, cb = colbase + 16 + m;
        const float bva = bias[ca], bvb = bias[cb];
        const float w0a = wc[ca * 2], w1a = wc[ca * 2 + 1];
        const float w0b = wc[cb * 2], w1b = wc[cb * 2 + 1];
#pragma unroll
        for (int mi = 0; mi < MI; mi++) {
#pragma unroll
            for (int r = 0; r < 4; r++) {
                int row = r0 + mi * 16 + q * 4 + r;
                float va = acc[mi][0][r] + bva;
                float vb = acc[mi][1][r] + bvb;
                float p0 = va * w0a + vb * w0b;
                float p1 = va * w1a + vb * w1b;
#pragma unroll
                for (int s = 1; s < 16; s <<= 1) {
                    p0 += __shfl_xor(p0, s);
                    p1 += __shfl_xor(p1, s);
                }
                if (m == 0 && row < M) {
                    atomicAdd(&outp[row * 2], p0);
                    atomicAdd(&outp[row * 2 + 1], p1);
                }
            }
        }
    }
}

// --- layer-0 mean-agg: wave/dst over G rows (384B), 4-edge pipelined -------
__global__ void k_agg0(const u16* __restrict__ G, const int* __restrict__ off,
                       const int* __restrict__ eidx, u16* __restrict__ aggH) {
    int wid = (blockIdx.x * blockDim.x + threadIdx.x) >> 6;
    int lane = threadIdx.x & 63;
    if (wid >= N1v) return;
    int b = off[wid], e = off[wid + 1];
    float f0 = 0.f, f1 = 0.f, p0 = 0.f;
    for (int base = b; base < e; base += 64) {
        int li = base + lane;
        int idx = eidx[li < e ? li : (e - 1)];
        int nch = e - base; if (nch > 64) nch = 64;
        int j = 0;
        for (; j + 4 <= nch; j += 4) {
            int sa = __shfl(idx, j), sb = __shfl(idx, j + 1);
            int sc = __shfl(idx, j + 2), sd = __shfl(idx, j + 3);
            const u16* ra = &G[(size_t)sa * 192];
            const u16* rb = &G[(size_t)sb * 192];
            const u16* rc = &G[(size_t)sc * 192];
            const u16* rd = &G[(size_t)sd * 192];
            unsigned fa = *(const unsigned*)&ra[2 * lane];
            unsigned fb = *(const unsigned*)&rb[2 * lane];
            unsigned fc = *(const unsigned*)&rc[2 * lane];
            unsigned fd = *(const unsigned*)&rd[2 * lane];
            u16 pa = ra[128 + lane], pb = rb[128 + lane];
            u16 pc = rc[128 + lane], pd = rd[128 + lane];
            f0 += b2f((u16)fa) + b2f((u16)fb) + b2f((u16)fc) + b2f((u16)fd);
            f1 += b2f((u16)(fa >> 16)) + b2f((u16)(fb >> 16)) +
                  b2f((u16)(fc >> 16)) + b2f((u16)(fd >> 16));
            p0 += b2f(pa) + b2f(pb) + b2f(pc) + b2f(pd);
        }
        for (; j < nch; j++) {
            int s = __shfl(idx, j);
            const u16* row = &G[(size_t)s * 192];
            unsigned fv = *(const unsigned*)&row[2 * lane];
            f0 += b2f((u16)fv);
            f1 += b2f((u16)(fv >> 16));
            p0 += b2f(row[128 + lane]);
        }
    }
    int deg = e - b;
    float inv = 1.0f / (float)(deg > 1 ? deg : 1);
    size_t rb2 = (size_t)wid * 192;
    *(unsigned*)&aggH[rb2 + 2 * lane] =
        (unsigned)f2b(f0 * inv) | ((unsigned)f2b(f1 * inv) << 16);
    aggH[rb2 + 128 + lane] = f2b(p0 * inv);
}

// --- layer-1 mean-agg: wave/dst over h1H rows (512B), 4-edge pipelined -----
__global__ void k_agg1(const u16* __restrict__ h1H, const int* __restrict__ off,
                       const int* __restrict__ eidx, u16* __restrict__ aggH) {
    int wid = (blockIdx.x * blockDim.x + threadIdx.x) >> 6;
    int lane = threadIdx.x & 63;
    if (wid >= N2v) return;
    int b = off[wid], e = off[wid + 1];
    float a0 = 0.f, a1 = 0.f, a2 = 0.f, a3 = 0.f;
    for (int base = b; base < e; base += 64) {
        int li = base + lane;
        int idx = eidx[li < e ? li : (e - 1)];
        int nch = e - base; if (nch > 64) nch = 64;
        int j = 0;
        for (; j + 4 <= nch; j += 4) {
            int sa = __shfl(idx, j), sb = __shfl(idx, j + 1);
            int sc = __shfl(idx, j + 2), sd = __shfl(idx, j + 3);
            const u16* ra = &h1H[(size_t)sa * 256];
            const u16* rb = &h1H[(size_t)sb * 256];
            const u16* rc = &h1H[(size_t)sc * 256];
            const u16* rd = &h1H[(size_t)sd * 256];
            unsigned va0 = *(const unsigned*)&ra[2 * lane];
            unsigned vb0 = *(const unsigned*)&rb[2 * lane];
            unsigned vc0 = *(const unsigned*)&rc[2 * lane];
            unsigned vd0 = *(const unsigned*)&rd[2 * lane];
            unsigned va1 = *(const unsigned*)&ra[128 + 2 * lane];
            unsigned vb1 = *(const unsigned*)&rb[128 + 2 * lane];
            unsigned vc1 = *(const unsigned*)&rc[128 + 2 * lane];
            unsigned vd1 = *(const unsigned*)&rd[128 + 2 * lane];
            a0 += b2f((u16)va0) + b2f((u16)vb0) + b2f((u16)vc0) + b2f((u16)vd0);
            a1 += b2f((u16)(va0 >> 16)) + b2f((u16)(vb0 >> 16)) +
                  b2f((u16)(vc0 >> 16)) + b2f((u16)(vd0 >> 16));
            a2 += b2f((u16)va1) + b2f((u16)vb1) + b2f((u16)vc1) + b2f((u16)vd1);
            a3 += b2f((u16)(va1 >> 16)) + b2f((u16)(vb1 >> 16)) +
                  b2f((u16)(vc1 >> 16)) + b2f((u16)(vd1 >> 16));
        }
        for (; j < nch; j++) {
            int s = __shfl(idx, j);
            const u16* row = &h1H[(size_t)s * 256];
            unsigned v0 = *(const unsigned*)&row[2 * lane];
            unsigned v1 = *(const unsigned*)&row[128 + 2 * lane];
            a0 += b2f((u16)v0); a1 += b2f((u16)(v0 >> 16));
            a2 += b2f((u16)v1); a3 += b2f((u16)(v1 >> 16));
        }
    }
    int deg = e - b;
    float inv = 1.0f / (float)(deg > 1 ? deg : 1);
    size_t rb2 = (size_t)wid * 256;
    *(unsigned*)&aggH[rb2 + 2 * lane] =
        (unsigned)f2b(a0 * inv) | ((unsigned)f2b(a1 * inv) << 16);
    *(unsigned*)&aggH[rb2 + 128 + 2 * lane] =
        (unsigned)f2b(a2 * inv) | ((unsigned)f2b(a3 * inv) << 16);
}

extern "C" void kernel_launch(void* const* d_in, const int* in_sizes, int n_in,
                              void* d_out, int out_size, void* d_ws, size_t ws_size,
                              hipStream_t stream) {
    const float* features = (const float*)d_in[0];
    const void* maskp     = d_in[1];
    const int* src0       = (const int*)d_in[2];
    const int* dst0       = (const int*)d_in[3];
    const int* src1       = (const int*)d_in[4];
    const int* dst1       = (const int*)d_in[5];
    const float* w_pin    = (const float*)d_in[7];
    const float* b_pin    = (const float*)d_in[8];
    const float* w_pout   = (const float*)d_in[9];
    const float* b_pout   = (const float*)d_in[10];
    const float* w_self0  = (const float*)d_in[11];
    const float* w_neigh0 = (const float*)d_in[12];
    const float* b0       = (const float*)d_in[13];
    const float* w_self1  = (const float*)d_in[14];
    const float* w_neigh1 = (const float*)d_in[15];
    const float* b1       = (const float*)d_in[16];
    const float* w_cls    = (const float*)d_in[17];
    const float* b_cls    = (const float*)d_in[18];
    float* out = (float*)d_out;
    (void)in_sizes; (void)n_in; (void)out_size; (void)ws_size;

    char* ws = (char*)d_ws;
    size_t o = 0;
    auto alloc = [&](size_t bytes) { size_t r = o; o += (bytes + 255) & ~(size_t)255; return r; };
    // zeroed block (one memset)
    size_t o_flag = alloc(4);
    size_t o_cnt0 = alloc(N1v * 4);
    size_t o_cnt1 = alloc(N2v * 4);
    size_t zero_end = o;
    // rest
    size_t o_G    = alloc((size_t)N0v * 192 * 2);   // 76.8 MB
    size_t o_aggH = alloc((size_t)N1v * 192 * 2);
    size_t o_h1H  = alloc((size_t)N1v * 256 * 2);
    size_t o_ag1H = alloc((size_t)N2v * 256 * 2);
    size_t o_wtph = alloc(128 * 128 * 2), o_wtpl = alloc(128 * 128 * 2);
    size_t o_wt0h = alloc(256 * 384 * 2), o_wt0l = alloc(256 * 384 * 2);
    size_t o_wt1h = alloc(256 * 512 * 2), o_wt1l = alloc(256 * 512 * 2);
    size_t o_off0 = alloc((N1v + 1) * 4);
    size_t o_off1 = alloc((N2v + 1) * 4);
    size_t o_ei0  = alloc((size_t)E0v * 4);
    size_t o_ei1  = alloc((size_t)E1v * 4);
    size_t o_rk0  = alloc((size_t)E0v * 4);
    size_t o_rk1  = alloc((size_t)E1v * 4);
    size_t o_tsum = alloc(TBL * 4);

    int* flag = (int*)(ws + o_flag);
    int* cnt0 = (int*)(ws + o_cnt0);
    int* cnt1 = (int*)(ws + o_cnt1);
    u16* G     = (u16*)(ws + o_G);
    u16* aggH  = (u16*)(ws + o_aggH);
    u16* h1H   = (u16*)(ws + o_h1H);
    u16* ag1H  = (u16*)(ws + o_ag1H);
    u16* WTph = (u16*)(ws + o_wtph);
    u16* WTpl = (u16*)(ws + o_wtpl);
    u16* WT0h = (u16*)(ws + o_wt0h);
    u16* WT0l = (u16*)(ws + o_wt0l);
    u16* WT1h = (u16*)(ws + o_wt1h);
    u16* WT1l = (u16*)(ws + o_wt1l);
    int* off0 = (int*)(ws + o_off0);
    int* off1 = (int*)(ws + o_off1);
    int* ei0  = (int*)(ws + o_ei0);
    int* ei1  = (int*)(ws + o_ei1);
    int* rk0  = (int*)(ws + o_rk0);
    int* rk1  = (int*)(ws + o_rk1);
    int* tsum = (int*)(ws + o_tsum);

    // 1: zero flag + counters in one memset
    hipMemsetAsync(ws + o_flag, 0, zero_end - o_flag, stream);

    // 2: prep (misc: detect + weight splits + out init)
    k_prep<<<512, 256, 0, stream>>>((const unsigned*)maskp, flag,
                                    w_pin, w_pout, WTph, WTpl,
                                    w_self0, w_neigh0, WT0h, WT0l,
                                    w_self1, w_neigh1, WT1h, WT1l,
                                    b_cls, out);

    // 3: prompt GEMM (persistent) + FUSED count/rank
    k_gemm_p<<<PGRID, 256, 0, stream>>>(features, WTph, WTpl,
                                        b_pin, b_pout, maskp, flag, G,
                                        dst0, dst1, cnt0, cnt1, rk0, rk1);

    // 4-5: hierarchical scan (both graphs)
    k_scan_a<<<TBL, 256, 0, stream>>>(cnt0, off0, cnt1, off1, tsum);
    k_scan_c<<<TBL, 256, 0, stream>>>(off0, off1, tsum);

    // 6: edge scatter (atomic-free, XCD-partitioned)
    k_scatter2<<<2048, 256, 0, stream>>>(src0, dst0, off0, rk0, ei0,
                                         src1, dst1, off1, rk1, ei1);

    // 7: layer-0 mean agg -> aggH[N1,192]
    k_agg0<<<(N1v + 3) / 4, 256, 0, stream>>>(G, off0, ei0, aggH);

    // 8: h1 = relu([G | agg] @ WT0 + b0) -> h1H[N1,256]  (K=384, MT=64)
    k_g<1, 12, 192, 64><<<((N1v + 63) / 64) * 2, 256, 0, stream>>>(
        G, 192, aggH, 192, WT0h, WT0l, b0, h1H, nullptr, nullptr, N1v);

    // 9: layer-1 mean agg -> ag1H[N2,256]
    k_agg1<<<(N2v + 3) / 4, 256, 0, stream>>>(h1H, off1, ei1, ag1H);

    // 10: logits = ([h1|agg1] @ WT1 + b1) @ w_cls + b_cls  (fused, K=512, MT=32)
    k_g<3, 16, 256, 32><<<((N2v + 31) / 32) * 2, 256, 0, stream>>>(
        h1H, 256, ag1H, 256, WT1h, WT1l, b1, nullptr, out, w_cls, N2v);
}